// Round 9
// baseline (229.991 us; speedup 1.0000x reference)
//
#include <hip/hip_runtime.h>

typedef float floatx4 __attribute__((ext_vector_type(4)));
typedef float floatx16 __attribute__((ext_vector_type(16)));
typedef __bf16 bf16x8 __attribute__((ext_vector_type(8)));
typedef unsigned short u16x8 __attribute__((ext_vector_type(8)));
typedef unsigned short u16x4 __attribute__((ext_vector_type(4)));

#define GLDS16(g, l) __builtin_amdgcn_global_load_lds( \
    (__attribute__((address_space(1))) void*)(g), \
    (__attribute__((address_space(3))) void*)(l), 16, 0, 0)

__device__ __forceinline__ unsigned short f2bf(float f) {
    unsigned u = __float_as_uint(f);
    u += 0x7fffu + ((u >> 16) & 1u);   // RNE; inputs finite
    return (unsigned short)(u >> 16);
}

#if __has_builtin(__builtin_amdgcn_cvt_pk_bf16_f32)
__device__ __forceinline__ unsigned pk2(float a, float b) {
    typedef __bf16 bf16x2 __attribute__((ext_vector_type(2)));
    union { bf16x2 v; unsigned u; } cv;
    cv.v = __builtin_amdgcn_cvt_pk_bf16_f32(a, b);
    return cv.u;
}
#else
__device__ __forceinline__ unsigned pk2(float a, float b) {
    return (unsigned)f2bf(a) | ((unsigned)f2bf(b) << 16);
}
#endif

#if __has_builtin(__builtin_amdgcn_exp2f)
__device__ __forceinline__ float fast_exp2(float x) { return __builtin_amdgcn_exp2f(x); }
#else
__device__ __forceinline__ float fast_exp2(float x) { return __exp2f(x); }
#endif

// ---------------- kernel 1: fused prep ----------------
__global__ __launch_bounds__(256) void k_prep(const float* __restrict__ hidden,
                                              const float* __restrict__ Wqk,
                                              const float* __restrict__ Wv,
                                              unsigned short* __restrict__ Abf,
                                              unsigned short* __restrict__ Wt) {
    __shared__ unsigned short t[64][68];
    const int tid = threadIdx.x;
    if (blockIdx.x < 2048) {
        int idx = (blockIdx.x * 256 + tid) * 8;
        const float4* p = (const float4*)(hidden + idx);
        float4 f0 = p[0], f1 = p[1];
        u16x8 o;
        o[0] = f2bf(f0.x); o[1] = f2bf(f0.y); o[2] = f2bf(f0.z); o[3] = f2bf(f0.w);
        o[4] = f2bf(f1.x); o[5] = f2bf(f1.y); o[6] = f2bf(f1.z); o[7] = f2bf(f1.w);
        *(u16x8*)(Abf + idx) = o;
        return;
    }
    const int bx = blockIdx.x - 2048;      // 768 = 48 n-tiles x 16 k-tiles
    const int n0 = (bx % 48) * 64;
    const int k0 = (bx / 48) * 64;
    const int nl = tid & 63;
    const int kb = tid >> 6;
    const int ng = n0 + nl;
#pragma unroll
    for (int i = 0; i < 16; ++i) {
        int kl = kb + i * 4;
        float v = (n0 < 2048) ? Wqk[(size_t)(k0 + kl) * 2048 + ng]
                              : Wv[(size_t)(k0 + kl) * 1024 + (ng - 2048)];
        t[nl][kl] = f2bf(v);
    }
    __syncthreads();
    const int k4 = (tid & 15) * 4;
    const int nb = tid >> 4;
#pragma unroll
    for (int i = 0; i < 4; ++i) {
        int n2 = nb + i * 16;
        u16x4 o;
        o[0] = t[n2][k4]; o[1] = t[n2][k4 + 1]; o[2] = t[n2][k4 + 2]; o[3] = t[n2][k4 + 3];
        *(u16x4*)(Wt + (size_t)(n0 + n2) * 1024 + k0 + k4) = o;
    }
}

// ---------------- kernel 2: QKV GEMM, fragment-packed LDS staging ----------------
// global_load_lds global side is per-lane addressed; only the LDS side is
// base+lane*16. So we gather each 16-row x 32-k MFMA fragment directly into
// fragment order: lane L <- A[m0+mt*16+(L&15)][k0+kh*32+(L>>4)*8]. Global
// pattern unchanged (16 rows x 64B full sectors); every K-loop ds_read_b128
// becomes stride-1 lane*16 -> 2-way bank aliasing only (free).
// Q/K n-tiles compute C^T (operand swap; A/B frag layouts identical) so all
// epilogue stores are dense u16x4.
__global__ __launch_bounds__(256, 3) void k_gemm_qkv(
    const unsigned short* __restrict__ A,
    const unsigned short* __restrict__ Bt,
    const float* __restrict__ bqk, const float* __restrict__ bvv,
    unsigned short* __restrict__ Qf, unsigned short* __restrict__ Kf,
    unsigned short* __restrict__ Vf) {
    __shared__ unsigned short As[16 * 512];   // 16 fragments x 1KB; frag = mt*2+kh
    __shared__ unsigned short Bs[16 * 512];
    const int tid = threadIdx.x;
    const int lane = tid & 63;
    const int w = tid >> 6;
    const int l15 = lane & 15;
    const int quad = lane >> 4;
    const int gb = blockIdx.x;
    const int q = gb >> 3;
    const int m0 = ((((gb & 7) << 2) | (q & 3))) * 128;   // 32 m-tiles (XCD slab)
    const int n0 = (q >> 2) * 128;                        // 24 n-tiles
    const bool isV = (n0 >= 2048);
    const int wmt = (w & 1) * 4;   // wave's A subtile base (16-row units)
    const int wnt = (w >> 1) * 4;  // wave's B subtile base
    const int wm = wmt * 16;
    const int wn = wnt * 16;

    floatx4 acc[4][4] = {};

    // each wave stages fragments fr = w*4 .. w*4+3 of both A and B
    const unsigned short* ag[4];
    const unsigned short* bg[4];
    unsigned short* al[4];
    unsigned short* bl[4];
#pragma unroll
    for (int i = 0; i < 4; ++i) {
        const int fr = w * 4 + i;
        const int mt = fr >> 1, kh = fr & 1;
        ag[i] = A  + (size_t)(m0 + mt * 16 + l15) * 1024 + kh * 32 + quad * 8;
        bg[i] = Bt + (size_t)(n0 + mt * 16 + l15) * 1024 + kh * 32 + quad * 8;
        al[i] = As + fr * 512;
        bl[i] = Bs + fr * 512;
    }

    for (int k0 = 0; k0 < 1024; k0 += 64) {
#pragma unroll
        for (int i = 0; i < 4; ++i) {
            GLDS16(ag[i] + k0, al[i]);
            GLDS16(bg[i] + k0, bl[i]);
        }
        __syncthreads();
#pragma unroll
        for (int h = 0; h < 2; ++h) {
            bf16x8 af[4], bfr[4];
#pragma unroll
            for (int mi = 0; mi < 4; ++mi)
                af[mi] = *(const bf16x8*)(As + ((wmt + mi) * 2 + h) * 512 + lane * 8);
#pragma unroll
            for (int ni = 0; ni < 4; ++ni)
                bfr[ni] = *(const bf16x8*)(Bs + ((wnt + ni) * 2 + h) * 512 + lane * 8);
            if (!isV) {   // C^T: rows=n, cols=m
#pragma unroll
                for (int mi = 0; mi < 4; ++mi)
#pragma unroll
                    for (int ni = 0; ni < 4; ++ni)
                        acc[mi][ni] = __builtin_amdgcn_mfma_f32_16x16x32_bf16(bfr[ni], af[mi],
                                                                              acc[mi][ni], 0, 0, 0);
            } else {      // C: rows=m, cols=n
#pragma unroll
                for (int mi = 0; mi < 4; ++mi)
#pragma unroll
                    for (int ni = 0; ni < 4; ++ni)
                        acc[mi][ni] = __builtin_amdgcn_mfma_f32_16x16x32_bf16(af[mi], bfr[ni],
                                                                              acc[mi][ni], 0, 0, 0);
            }
        }
        __syncthreads();
    }
    if (!isV) {
        // Q/K epilogue from C^T: lane = fixed s (col=l15), rows = 4 consecutive d.
        const bool isQ = (n0 < 1024);
        unsigned short* dst = isQ ? Qf : Kf;
        const float scale = isQ ? 0.18033688011112042f : 1.0f;  // log2(e)/8
#pragma unroll
        for (int mi = 0; mi < 4; ++mi) {
            const int m = m0 + wm + mi * 16 + l15;
            const int b = m >> 11, s = m & 2047;
            const int t = s >> 5, cc = s & 31;
#pragma unroll
            for (int ni = 0; ni < 4; ++ni) {
                const int nb = n0 + wn + ni * 16 + (quad << 2);   // n for r=0
                const float4 bq = *(const float4*)(bqk + nb);
                const int hd = isQ ? nb : nb - 1024;
                const int h = hd >> 6, d = hd & 63;
                const int kb = d >> 4, hhd = (d >> 3) & 1, jj = d & 7;  // jj in {0,4}
                const int bh = b * 16 + h;
                u16x4 o4;
                o4[0] = f2bf((acc[mi][ni][0] + bq.x) * scale);
                o4[1] = f2bf((acc[mi][ni][1] + bq.y) * scale);
                o4[2] = f2bf((acc[mi][ni][2] + bq.z) * scale);
                o4[3] = f2bf((acc[mi][ni][3] + bq.w) * scale);
                size_t idx = ((((size_t)(bh * 64 + t) * 4 + kb) * 2 + hhd) * 32 + cc) * 8 + jj;
                *(u16x4*)(dst + idx) = o4;
            }
        }
    } else {
#pragma unroll
        for (int ni = 0; ni < 4; ++ni) {
            const int n = n0 + wn + ni * 16 + l15;
            const float bias = bvv[n - 2048];
            const int hd = n - 2048;
            const int h = hd >> 6, d = hd & 63;
            const int dt = d >> 5, cc = d & 31;
#pragma unroll
            for (int mi = 0; mi < 4; ++mi) {
                const int m = m0 + wm + mi * 16 + (quad << 2);
                const int b = m >> 11, s = m & 2047;
                const int bh = b * 16 + h, t = s >> 5, kvr = s & 31;
                const int mb = kvr >> 4, hhv = (kvr >> 3) & 1, jj0 = s & 7;
                u16x4 o4;
#pragma unroll
                for (int r = 0; r < 4; ++r) o4[r] = f2bf(acc[mi][ni][r] + bias);
                size_t idx = (((((size_t)(bh * 64 + t) * 2 + mb) * 2 + dt) * 2 + hhv) * 32 + cc) * 8 + jj0;
                *(u16x4*)(Vf + idx) = o4;
            }
        }
    }
}

// ---------------- kernel 3: L1-shared causal flash attention ----------------
// 768 blocks x 256 thr (4 waves). The 4 waves process q-tiles {4a..4a+3} over
// the SAME t-chunk: identical K/V addresses -> loads hit per-CU L1.
__global__ __launch_bounds__(256, 3) void k_attn(
    const unsigned short* __restrict__ Qf, const unsigned short* __restrict__ Kf,
    const unsigned short* __restrict__ Vf, float* __restrict__ out,
    float* __restrict__ Op1, float* __restrict__ l0, float* __restrict__ l1) {
    const int tid = threadIdx.x;
    const int lane = tid & 63;
    const int w = tid >> 6;
    const int c = lane & 31;
    const int hh = lane >> 5;
    const int gb = blockIdx.x;
    const int xcd = gb & 7;
    const int idx = gb >> 3;                   // 0..95
    const int bh = xcd + ((idx & 3) << 3);     // XCD-affine head mapping
    const int u = idx >> 2;                    // 0..23, LPT-ordered
    int a, mode;
    if (u < 8) { a = 8 + u; mode = 1; }
    else {
        const int i = u - 8;
        if ((i & 1) == 0) { a = 7 - (i >> 1); mode = 0; }
        else              { a = 15 - (i >> 1); mode = 2; }
    }
    const int j = 4 * a + w;                   // this wave's q-tile
    const int t0 = (mode == 2) ? 32 : 0;
    const int t1 = (mode == 1) ? 31 : j;
    const int q_abs = j * 32 + c;

    bf16x8 qf[4];
    {
        const unsigned short* qp = Qf + (size_t)(bh * 64 + j) * 2048 + lane * 8;
#pragma unroll
        for (int kb = 0; kb < 4; ++kb) qf[kb] = *(const bf16x8*)(qp + kb * 512);
    }
    const unsigned short* kbase = Kf + (size_t)bh * (64 * 2048) + lane * 8;
    const unsigned short* vbase = Vf + (size_t)bh * (64 * 2048) + lane * 8;

    floatx16 o2[2] = {};           // O^T: d = dt*32 + (i&3)+8*(i>>2)+4*hh, col q=c
    float ls0 = 0.f, ls1 = 0.f;

    bf16x8 kf[4];
    {
        const unsigned short* kp = kbase + (size_t)t0 * 2048;
#pragma unroll
        for (int kb = 0; kb < 4; ++kb) kf[kb] = *(const bf16x8*)(kp + kb * 512);
    }

    for (int t = t0; t <= t1; ++t) {
        const unsigned short* vp = vbase + (size_t)t * 2048;
        bf16x8 vf[4];  // [mb*2+dt]
#pragma unroll
        for (int f = 0; f < 4; ++f) vf[f] = *(const bf16x8*)(vp + f * 512);

        // S^T = K·Q^T : C rows kv_rel = (i&3)+8*(i>>2)+4*hh, col q = c
        floatx16 st = {};
#pragma unroll
        for (int kb = 0; kb < 4; ++kb)
            st = __builtin_amdgcn_mfma_f32_32x32x16_bf16(kf[kb], qf[kb], st, 0, 0, 0);

        bf16x8 kn[4];
        if (t < t1) {
            const unsigned short* kpn = kbase + (size_t)(t + 1) * 2048;
#pragma unroll
            for (int kb = 0; kb < 4; ++kb) kn[kb] = *(const bf16x8*)(kpn + kb * 512);
        }

        if (t == j) {  // diagonal: causal mask (kv_rel > c); never taken in mode1
#pragma unroll
            for (int i = 0; i < 16; ++i) {
                const int kvr = (i & 3) + 8 * (i >> 2) + 4 * hh;
                if (kvr > c) st[i] = -1e30f;
            }
        }

        float a0 = 0.f, a1 = 0.f, a2 = 0.f, a3 = 0.f;
#pragma unroll
        for (int i = 0; i < 16; i += 4) {
            float p0 = fast_exp2(st[i + 0]);
            float p1 = fast_exp2(st[i + 1]);
            float p2 = fast_exp2(st[i + 2]);
            float p3 = fast_exp2(st[i + 3]);
            st[i + 0] = p0; st[i + 1] = p1; st[i + 2] = p2; st[i + 3] = p3;
            a0 += p0; a1 += p1; a2 += p2; a3 += p3;
        }
        ls0 += a0 + a2; ls1 += a1 + a3;

        // P^T B-frags (pack + lane^32 half exchange), then O^T += V^T·P^T
#pragma unroll
        for (int mb = 0; mb < 2; ++mb) {
            const int rb = mb * 8;
            unsigned p0 = pk2(st[rb + 0], st[rb + 1]);
            unsigned p1 = pk2(st[rb + 2], st[rb + 3]);
            unsigned p2 = pk2(st[rb + 4], st[rb + 5]);
            unsigned p3 = pk2(st[rb + 6], st[rb + 7]);
            unsigned sA = hh ? p0 : p2;
            unsigned sB = hh ? p1 : p3;
            unsigned rA = (unsigned)__shfl_xor((int)sA, 32, 64);
            unsigned rB = (unsigned)__shfl_xor((int)sB, 32, 64);
            union { unsigned u4[4]; bf16x8 v; } pf;
            if (hh == 0) { pf.u4[0] = p0; pf.u4[1] = p1; pf.u4[2] = rA; pf.u4[3] = rB; }
            else         { pf.u4[0] = rA; pf.u4[1] = rB; pf.u4[2] = p2; pf.u4[3] = p3; }
#pragma unroll
            for (int dt = 0; dt < 2; ++dt)
                o2[dt] = __builtin_amdgcn_mfma_f32_32x32x16_bf16(vf[mb * 2 + dt], pf.v,
                                                                 o2[dt], 0, 0, 0);
        }
#pragma unroll
        for (int kb = 0; kb < 4; ++kb) kf[kb] = kn[kb];
    }

    const int b = bh >> 4, head = bh & 15;
    float lrow = ls0 + ls1;
    lrow += __shfl_xor(lrow, 32, 64);
    if (mode == 0) {
        const float inv = 1.0f / lrow;
        float* op = out + (size_t)(b * 2048 + q_abs) * 1024 + head * 64;
#pragma unroll
        for (int dt = 0; dt < 2; ++dt)
#pragma unroll
            for (int rr = 0; rr < 4; ++rr) {
                float4 v4 = make_float4(o2[dt][rr * 4 + 0] * inv, o2[dt][rr * 4 + 1] * inv,
                                        o2[dt][rr * 4 + 2] * inv, o2[dt][rr * 4 + 3] * inv);
                *(float4*)(op + dt * 32 + rr * 8 + hh * 4) = v4;
            }
    } else {
        const int qr = q_abs - 1024;   // partial units have j>=32
        float* op;
        if (mode == 1) {
            if (hh == 0) l0[bh * 1024 + qr] = lrow;
            op = out + (size_t)(b * 2048 + q_abs) * 1024 + head * 64;
        } else {
            if (hh == 0) l1[bh * 1024 + qr] = lrow;
            op = Op1 + (size_t)(bh * 1024 + qr) * 64;
        }
#pragma unroll
        for (int dt = 0; dt < 2; ++dt)
#pragma unroll
            for (int rr = 0; rr < 4; ++rr) {
                float4 v4 = make_float4(o2[dt][rr * 4 + 0], o2[dt][rr * 4 + 1],
                                        o2[dt][rr * 4 + 2], o2[dt][rr * 4 + 3]);
                *(float4*)(op + dt * 32 + rr * 8 + hh * 4) = v4;
            }
    }
}

// ---------------- kernel 4: combine the two kv-chunks for q>=1024 ----------------
__global__ __launch_bounds__(256) void k_comb(const float* __restrict__ Op1,
                                              const float* __restrict__ l0,
                                              const float* __restrict__ l1,
                                              float* __restrict__ out) {
    const int idx = blockIdx.x * 256 + threadIdx.x;   // 524288 float4s
    const int bh = idx >> 14;
    const int rem = idx & 16383;
    const int qr = rem >> 4;
    const int d4 = (rem & 15) << 2;
    const float inv = 1.0f / (l0[bh * 1024 + qr] + l1[bh * 1024 + qr]);
    const int b = bh >> 4, h = bh & 15;
    float* op = out + (size_t)(b * 2048 + 1024 + qr) * 1024 + h * 64 + d4;
    const float* pp = Op1 + (size_t)(bh * 1024 + qr) * 64 + d4;
    float4 a = *(const float4*)op;
    float4 p = *(const float4*)pp;
    float4 r = make_float4((a.x + p.x) * inv, (a.y + p.y) * inv,
                           (a.z + p.z) * inv, (a.w + p.w) * inv);
    *(float4*)op = r;
}

extern "C" void kernel_launch(void* const* d_in, const int* in_sizes, int n_in,
                              void* d_out, int out_size, void* d_ws, size_t ws_size,
                              hipStream_t stream) {
    const float* hidden = (const float*)d_in[0];
    const float* Wqk    = (const float*)d_in[1];
    const float* bqk    = (const float*)d_in[2];
    const float* Wv     = (const float*)d_in[3];
    const float* bvv    = (const float*)d_in[4];
    float* out = (float*)d_out;

    unsigned short* Abf = (unsigned short*)d_ws;        // dead after gemm
    unsigned short* Wt  = Abf + 4096 * 1024;            // dead after gemm
    unsigned short* Qf  = Wt + 3072 * 1024;             // packed, 8.39 MB each
    unsigned short* Kf  = Qf + 32 * 2048 * 64;
    unsigned short* Vf  = Kf + 32 * 2048 * 64;
    float* Op1 = (float*)d_ws;                          // aliases dead regions
    float* l0  = Op1 + 32 * 1024 * 64;
    float* l1  = l0 + 32 * 1024;

    k_prep<<<2816, 256, 0, stream>>>(hidden, Wqk, Wv, Abf, Wt);
    k_gemm_qkv<<<768, 256, 0, stream>>>(Abf, Wt, bqk, bvv, Qf, Kf, Vf);
    k_attn<<<768, 256, 0, stream>>>(Qf, Kf, Vf, out, Op1, l0, l1);
    k_comb<<<2048, 256, 0, stream>>>(Op1, l0, l1, out);
}

// Round 10
// 150.958 us; speedup vs baseline: 1.5235x; 1.5235x over previous
//
#include <hip/hip_runtime.h>

typedef float floatx4 __attribute__((ext_vector_type(4)));
typedef float floatx16 __attribute__((ext_vector_type(16)));
typedef __bf16 bf16x8 __attribute__((ext_vector_type(8)));
typedef unsigned short u16x8 __attribute__((ext_vector_type(8)));
typedef unsigned short u16x4 __attribute__((ext_vector_type(4)));

__device__ __forceinline__ unsigned short f2bf(float f) {
    unsigned u = __float_as_uint(f);
    u += 0x7fffu + ((u >> 16) & 1u);   // RNE; inputs finite
    return (unsigned short)(u >> 16);
}

#if __has_builtin(__builtin_amdgcn_cvt_pk_bf16_f32)
__device__ __forceinline__ unsigned pk2(float a, float b) {
    typedef __bf16 bf16x2 __attribute__((ext_vector_type(2)));
    union { bf16x2 v; unsigned u; } cv;
    cv.v = __builtin_amdgcn_cvt_pk_bf16_f32(a, b);
    return cv.u;
}
#else
__device__ __forceinline__ unsigned pk2(float a, float b) {
    return (unsigned)f2bf(a) | ((unsigned)f2bf(b) << 16);
}
#endif

#if __has_builtin(__builtin_amdgcn_exp2f)
__device__ __forceinline__ float fast_exp2(float x) { return __builtin_amdgcn_exp2f(x); }
#else
__device__ __forceinline__ float fast_exp2(float x) { return __exp2f(x); }
#endif

// ---------------- kernel 1: fused prep -> fragment-packed Af / Wtf ----------------
// Af layout : frag (mt=m>>4, kc=k>>5): lane=(m&15)+16*((k>>3)&3) holds 8 bf16 of
//             A[m][kc*32 + (lane>>4)*8 .. +8]; addr = ((mt*32+kc)*64+lane)*8.
// Wtf same form over W^T rows (n index).  All writes are dense 1KB wave bursts.
// blocks [0,512): hidden convert (mt = bx>>1, half of kcs each)
// blocks [512,1280): weight transpose via LDS tile, packed output
__global__ __launch_bounds__(256) void k_prep(const float* __restrict__ hidden,
                                              const float* __restrict__ Wqk,
                                              const float* __restrict__ Wv,
                                              unsigned short* __restrict__ Af,
                                              unsigned short* __restrict__ Wtf) {
    __shared__ unsigned short t[64][68];
    const int tid = threadIdx.x;
    const int lane = tid & 63;
    const int w = tid >> 6;
    const int l15 = lane & 15;
    const int quad = lane >> 4;
    if (blockIdx.x < 512) {
        const int mt = blockIdx.x >> 1;
        const int half = blockIdx.x & 1;
        const int m0 = mt * 16;
#pragma unroll
        for (int r = 0; r < 4; ++r) {
            const int kc = half * 16 + r * 4 + w;
            const float* src = hidden + (size_t)(m0 + l15) * 1024 + kc * 32 + quad * 8;
            float4 a = *(const float4*)src;
            float4 b = *(const float4*)(src + 4);
            u16x8 o;
            o[0] = f2bf(a.x); o[1] = f2bf(a.y); o[2] = f2bf(a.z); o[3] = f2bf(a.w);
            o[4] = f2bf(b.x); o[5] = f2bf(b.y); o[6] = f2bf(b.z); o[7] = f2bf(b.w);
            *(u16x8*)(Af + ((size_t)(mt * 32 + kc) * 64 + lane) * 8) = o;
        }
        return;
    }
    const int bx = blockIdx.x - 512;       // 768 = 48 n-tiles x 16 k-tiles
    const int n0 = (bx % 48) * 64;
    const int k0 = (bx / 48) * 64;
    const int nl = tid & 63;
    const int kb = tid >> 6;
    const int ng = n0 + nl;
#pragma unroll
    for (int i = 0; i < 16; ++i) {
        int kl = kb + i * 4;
        float v = (n0 < 2048) ? Wqk[(size_t)(k0 + kl) * 2048 + ng]
                              : Wv[(size_t)(k0 + kl) * 1024 + (ng - 2048)];
        t[nl][kl] = f2bf(v);
    }
    __syncthreads();
    // write 2 packed 16B pieces per thread (dense 1KB per wave-instruction)
#pragma unroll
    for (int pi = 0; pi < 2; ++pi) {
        const int p = tid + pi * 256;
        const int ntl = p >> 7;            // 0..3
        const int kcl = (p >> 6) & 1;      // 0..1
        const int lo = p & 63;
        const int nloc = ntl * 16 + (lo & 15);
        const int kloc = kcl * 32 + (lo >> 4) * 8;
        u16x8 o;
#pragma unroll
        for (int j = 0; j < 8; ++j) o[j] = t[nloc][kloc + j];
        const int nt_g = (n0 >> 4) + ntl;
        const int kc_g = (k0 >> 5) + kcl;
        *(u16x8*)(Wtf + ((size_t)(nt_g * 32 + kc_g) * 64 + lo) * 8) = o;
    }
}

// ---------------- kernel 2: QKV GEMM, no LDS, fragment-direct K-loop ----------------
// 768 blocks (XCD slab swizzle) x 4 waves over a 128x128 tile. Per kc-step a
// wave loads 4 A-frags + 4 B-frags as contiguous 1KB bursts (wave pairs share
// addresses -> L1 hits), does 16 MFMAs, prefetches step kc+1 in registers.
// Q/K n-tiles compute C^T (free operand swap) -> dense u16x4 epilogue stores.
__global__ __launch_bounds__(256, 3) void k_gemm_qkv(
    const unsigned short* __restrict__ Af,
    const unsigned short* __restrict__ Wtf,
    const float* __restrict__ bqk, const float* __restrict__ bvv,
    unsigned short* __restrict__ Qf, unsigned short* __restrict__ Kf,
    unsigned short* __restrict__ Vf) {
    const int tid = threadIdx.x;
    const int lane = tid & 63;
    const int w = tid >> 6;
    const int l15 = lane & 15;
    const int quad = lane >> 4;
    const int gb = blockIdx.x;
    const int q = gb >> 3;
    const int m0 = ((((gb & 7) << 2) | (q & 3))) * 128;   // 32 m-tiles (XCD slab)
    const int n0 = (q >> 2) * 128;                        // 24 n-tiles
    const bool isV = (n0 >= 2048);
    const int wm = (w & 1) * 64;
    const int wn = (w >> 1) * 64;

    const unsigned short* Ab = Af  + ((size_t)((m0 >> 4) + (w & 1) * 4) * 32) * 512 + lane * 8;
    const unsigned short* Bb = Wtf + ((size_t)((n0 >> 4) + (w >> 1) * 4) * 32) * 512 + lane * 8;

    floatx4 acc[4][4] = {};
    bf16x8 af[4], bfr[4];
#pragma unroll
    for (int i = 0; i < 4; ++i) {
        af[i]  = *(const bf16x8*)(Ab + (size_t)(i * 32) * 512);
        bfr[i] = *(const bf16x8*)(Bb + (size_t)(i * 32) * 512);
    }

    for (int kc = 0; kc < 32; ++kc) {
        bf16x8 an[4], bn[4];
        if (kc < 31) {
#pragma unroll
            for (int i = 0; i < 4; ++i) {
                an[i] = *(const bf16x8*)(Ab + (size_t)(i * 32 + kc + 1) * 512);
                bn[i] = *(const bf16x8*)(Bb + (size_t)(i * 32 + kc + 1) * 512);
            }
        }
        if (!isV) {   // C^T: rows=n, cols=m
#pragma unroll
            for (int mi = 0; mi < 4; ++mi)
#pragma unroll
                for (int ni = 0; ni < 4; ++ni)
                    acc[mi][ni] = __builtin_amdgcn_mfma_f32_16x16x32_bf16(bfr[ni], af[mi],
                                                                          acc[mi][ni], 0, 0, 0);
        } else {      // C: rows=m, cols=n
#pragma unroll
            for (int mi = 0; mi < 4; ++mi)
#pragma unroll
                for (int ni = 0; ni < 4; ++ni)
                    acc[mi][ni] = __builtin_amdgcn_mfma_f32_16x16x32_bf16(af[mi], bfr[ni],
                                                                          acc[mi][ni], 0, 0, 0);
        }
#pragma unroll
        for (int i = 0; i < 4; ++i) { af[i] = an[i]; bfr[i] = bn[i]; }
    }

    if (!isV) {
        // Q/K epilogue from C^T: lane = fixed s (col=l15), rows = 4 consecutive d.
        const bool isQ = (n0 < 1024);
        unsigned short* dst = isQ ? Qf : Kf;
        const float scale = isQ ? 0.18033688011112042f : 1.0f;  // log2(e)/8
#pragma unroll
        for (int mi = 0; mi < 4; ++mi) {
            const int m = m0 + wm + mi * 16 + l15;
            const int b = m >> 11, s = m & 2047;
            const int t = s >> 5, cc = s & 31;
#pragma unroll
            for (int ni = 0; ni < 4; ++ni) {
                const int nb = n0 + wn + ni * 16 + (quad << 2);   // n for r=0
                const float4 bq = *(const float4*)(bqk + nb);
                const int hd = isQ ? nb : nb - 1024;
                const int h = hd >> 6, d = hd & 63;
                const int kb = d >> 4, hhd = (d >> 3) & 1, jj = d & 7;  // jj in {0,4}
                const int bh = b * 16 + h;
                u16x4 o4;
                o4[0] = f2bf((acc[mi][ni][0] + bq.x) * scale);
                o4[1] = f2bf((acc[mi][ni][1] + bq.y) * scale);
                o4[2] = f2bf((acc[mi][ni][2] + bq.z) * scale);
                o4[3] = f2bf((acc[mi][ni][3] + bq.w) * scale);
                size_t idx = ((((size_t)(bh * 64 + t) * 4 + kb) * 2 + hhd) * 32 + cc) * 8 + jj;
                *(u16x4*)(dst + idx) = o4;
            }
        }
    } else {
#pragma unroll
        for (int ni = 0; ni < 4; ++ni) {
            const int n = n0 + wn + ni * 16 + l15;
            const float bias = bvv[n - 2048];
            const int hd = n - 2048;
            const int h = hd >> 6, d = hd & 63;
            const int dt = d >> 5, cc = d & 31;
#pragma unroll
            for (int mi = 0; mi < 4; ++mi) {
                const int m = m0 + wm + mi * 16 + (quad << 2);
                const int b = m >> 11, s = m & 2047;
                const int bh = b * 16 + h, t = s >> 5, kvr = s & 31;
                const int mb = kvr >> 4, hhv = (kvr >> 3) & 1, jj0 = s & 7;
                u16x4 o4;
#pragma unroll
                for (int r = 0; r < 4; ++r) o4[r] = f2bf(acc[mi][ni][r] + bias);
                size_t idx = (((((size_t)(bh * 64 + t) * 2 + mb) * 2 + dt) * 2 + hhv) * 32 + cc) * 8 + jj0;
                *(u16x4*)(Vf + idx) = o4;
            }
        }
    }
}

// ---------------- kernel 3: L1-shared causal flash attention ----------------
__global__ __launch_bounds__(256, 3) void k_attn(
    const unsigned short* __restrict__ Qf, const unsigned short* __restrict__ Kf,
    const unsigned short* __restrict__ Vf, float* __restrict__ out,
    float* __restrict__ Op1, float* __restrict__ l0, float* __restrict__ l1) {
    const int tid = threadIdx.x;
    const int lane = tid & 63;
    const int w = tid >> 6;
    const int c = lane & 31;
    const int hh = lane >> 5;
    const int gb = blockIdx.x;
    const int xcd = gb & 7;
    const int idx = gb >> 3;                   // 0..95
    const int bh = xcd + ((idx & 3) << 3);     // XCD-affine head mapping
    const int u = idx >> 2;                    // 0..23, LPT-ordered
    int a, mode;
    if (u < 8) { a = 8 + u; mode = 1; }
    else {
        const int i = u - 8;
        if ((i & 1) == 0) { a = 7 - (i >> 1); mode = 0; }
        else              { a = 15 - (i >> 1); mode = 2; }
    }
    const int j = 4 * a + w;                   // this wave's q-tile
    const int t0 = (mode == 2) ? 32 : 0;
    const int t1 = (mode == 1) ? 31 : j;
    const int q_abs = j * 32 + c;

    bf16x8 qf[4];
    {
        const unsigned short* qp = Qf + (size_t)(bh * 64 + j) * 2048 + lane * 8;
#pragma unroll
        for (int kb = 0; kb < 4; ++kb) qf[kb] = *(const bf16x8*)(qp + kb * 512);
    }
    const unsigned short* kbase = Kf + (size_t)bh * (64 * 2048) + lane * 8;
    const unsigned short* vbase = Vf + (size_t)bh * (64 * 2048) + lane * 8;

    floatx16 o2[2] = {};           // O^T: d = dt*32 + (i&3)+8*(i>>2)+4*hh, col q=c
    float ls0 = 0.f, ls1 = 0.f;

    bf16x8 kf[4];
    {
        const unsigned short* kp = kbase + (size_t)t0 * 2048;
#pragma unroll
        for (int kb = 0; kb < 4; ++kb) kf[kb] = *(const bf16x8*)(kp + kb * 512);
    }

    for (int t = t0; t <= t1; ++t) {
        const unsigned short* vp = vbase + (size_t)t * 2048;
        bf16x8 vf[4];  // [mb*2+dt]
#pragma unroll
        for (int f = 0; f < 4; ++f) vf[f] = *(const bf16x8*)(vp + f * 512);

        floatx16 st = {};
#pragma unroll
        for (int kb = 0; kb < 4; ++kb)
            st = __builtin_amdgcn_mfma_f32_32x32x16_bf16(kf[kb], qf[kb], st, 0, 0, 0);

        bf16x8 kn[4];
        if (t < t1) {
            const unsigned short* kpn = kbase + (size_t)(t + 1) * 2048;
#pragma unroll
            for (int kb = 0; kb < 4; ++kb) kn[kb] = *(const bf16x8*)(kpn + kb * 512);
        }

        if (t == j) {  // diagonal: causal mask (kv_rel > c); never taken in mode1
#pragma unroll
            for (int i = 0; i < 16; ++i) {
                const int kvr = (i & 3) + 8 * (i >> 2) + 4 * hh;
                if (kvr > c) st[i] = -1e30f;
            }
        }

        float a0 = 0.f, a1 = 0.f, a2 = 0.f, a3 = 0.f;
#pragma unroll
        for (int i = 0; i < 16; i += 4) {
            float p0 = fast_exp2(st[i + 0]);
            float p1 = fast_exp2(st[i + 1]);
            float p2 = fast_exp2(st[i + 2]);
            float p3 = fast_exp2(st[i + 3]);
            st[i + 0] = p0; st[i + 1] = p1; st[i + 2] = p2; st[i + 3] = p3;
            a0 += p0; a1 += p1; a2 += p2; a3 += p3;
        }
        ls0 += a0 + a2; ls1 += a1 + a3;

#pragma unroll
        for (int mb = 0; mb < 2; ++mb) {
            const int rb = mb * 8;
            unsigned p0 = pk2(st[rb + 0], st[rb + 1]);
            unsigned p1 = pk2(st[rb + 2], st[rb + 3]);
            unsigned p2 = pk2(st[rb + 4], st[rb + 5]);
            unsigned p3 = pk2(st[rb + 6], st[rb + 7]);
            unsigned sA = hh ? p0 : p2;
            unsigned sB = hh ? p1 : p3;
            unsigned rA = (unsigned)__shfl_xor((int)sA, 32, 64);
            unsigned rB = (unsigned)__shfl_xor((int)sB, 32, 64);
            union { unsigned u4[4]; bf16x8 v; } pf;
            if (hh == 0) { pf.u4[0] = p0; pf.u4[1] = p1; pf.u4[2] = rA; pf.u4[3] = rB; }
            else         { pf.u4[0] = rA; pf.u4[1] = rB; pf.u4[2] = p2; pf.u4[3] = p3; }
#pragma unroll
            for (int dt = 0; dt < 2; ++dt)
                o2[dt] = __builtin_amdgcn_mfma_f32_32x32x16_bf16(vf[mb * 2 + dt], pf.v,
                                                                 o2[dt], 0, 0, 0);
        }
#pragma unroll
        for (int kb = 0; kb < 4; ++kb) kf[kb] = kn[kb];
    }

    const int b = bh >> 4, head = bh & 15;
    float lrow = ls0 + ls1;
    lrow += __shfl_xor(lrow, 32, 64);
    if (mode == 0) {
        const float inv = 1.0f / lrow;
        float* op = out + (size_t)(b * 2048 + q_abs) * 1024 + head * 64;
#pragma unroll
        for (int dt = 0; dt < 2; ++dt)
#pragma unroll
            for (int rr = 0; rr < 4; ++rr) {
                float4 v4 = make_float4(o2[dt][rr * 4 + 0] * inv, o2[dt][rr * 4 + 1] * inv,
                                        o2[dt][rr * 4 + 2] * inv, o2[dt][rr * 4 + 3] * inv);
                *(float4*)(op + dt * 32 + rr * 8 + hh * 4) = v4;
            }
    } else {
        const int qr = q_abs - 1024;   // partial units have j>=32
        float* op;
        if (mode == 1) {
            if (hh == 0) l0[bh * 1024 + qr] = lrow;
            op = out + (size_t)(b * 2048 + q_abs) * 1024 + head * 64;
        } else {
            if (hh == 0) l1[bh * 1024 + qr] = lrow;
            op = Op1 + (size_t)(bh * 1024 + qr) * 64;
        }
#pragma unroll
        for (int dt = 0; dt < 2; ++dt)
#pragma unroll
            for (int rr = 0; rr < 4; ++rr) {
                float4 v4 = make_float4(o2[dt][rr * 4 + 0], o2[dt][rr * 4 + 1],
                                        o2[dt][rr * 4 + 2], o2[dt][rr * 4 + 3]);
                *(float4*)(op + dt * 32 + rr * 8 + hh * 4) = v4;
            }
    }
}

// ---------------- kernel 4: combine the two kv-chunks for q>=1024 ----------------
__global__ __launch_bounds__(256) void k_comb(const float* __restrict__ Op1,
                                              const float* __restrict__ l0,
                                              const float* __restrict__ l1,
                                              float* __restrict__ out) {
    const int idx = blockIdx.x * 256 + threadIdx.x;   // 524288 float4s
    const int bh = idx >> 14;
    const int rem = idx & 16383;
    const int qr = rem >> 4;
    const int d4 = (rem & 15) << 2;
    const float inv = 1.0f / (l0[bh * 1024 + qr] + l1[bh * 1024 + qr]);
    const int b = bh >> 4, h = bh & 15;
    float* op = out + (size_t)(b * 2048 + 1024 + qr) * 1024 + h * 64 + d4;
    const float* pp = Op1 + (size_t)(bh * 1024 + qr) * 64 + d4;
    float4 a = *(const float4*)op;
    float4 p = *(const float4*)pp;
    float4 r = make_float4((a.x + p.x) * inv, (a.y + p.y) * inv,
                           (a.z + p.z) * inv, (a.w + p.w) * inv);
    *(float4*)op = r;
}

extern "C" void kernel_launch(void* const* d_in, const int* in_sizes, int n_in,
                              void* d_out, int out_size, void* d_ws, size_t ws_size,
                              hipStream_t stream) {
    const float* hidden = (const float*)d_in[0];
    const float* Wqk    = (const float*)d_in[1];
    const float* bqk    = (const float*)d_in[2];
    const float* Wv     = (const float*)d_in[3];
    const float* bvv    = (const float*)d_in[4];
    float* out = (float*)d_out;

    unsigned short* Af  = (unsigned short*)d_ws;        // packed A frags, dead after gemm
    unsigned short* Wtf = Af + 4096 * 1024;             // packed W^T frags, dead after gemm
    unsigned short* Qf  = Wtf + 3072 * 1024;            // packed, 8.39 MB each
    unsigned short* Kf  = Qf + 32 * 2048 * 64;
    unsigned short* Vf  = Kf + 32 * 2048 * 64;
    float* Op1 = (float*)d_ws;                          // aliases dead regions
    float* l0  = Op1 + 32 * 1024 * 64;
    float* l1  = l0 + 32 * 1024;

    k_prep<<<1280, 256, 0, stream>>>(hidden, Wqk, Wv, Af, Wtf);
    k_gemm_qkv<<<768, 256, 0, stream>>>(Af, Wtf, bqk, bvv, Qf, Kf, Vf);
    k_attn<<<768, 256, 0, stream>>>(Qf, Kf, Vf, out, Op1, l0, l1);
    k_comb<<<2048, 256, 0, stream>>>(Op1, l0, l1, out);
}